// Round 1
// baseline (4686.661 us; speedup 1.0000x reference)
//
#include <hip/hip_runtime.h>
#include <math.h>

#define B_ 8192
#define T_ 30
#define H_ 256
#define NG_ 1024  // 4*H
#define DT_ 0.03f

// ---------- fold kernels: Wf = W1(4xK) @ W2(KxN); bf = b1@W2 + bih + bhh ----------
__global__ void fold_w_kernel(const float* __restrict__ W1, const float* __restrict__ W2,
                              float* __restrict__ Wf, int K, int N) {
    int id = blockIdx.x * blockDim.x + threadIdx.x;
    if (id >= 4 * N) return;
    int r = id / N, n = id % N;
    float acc = 0.f;
    for (int k = 0; k < K; ++k) acc = fmaf(W1[r * K + k], W2[k * N + n], acc);
    Wf[r * N + n] = acc;
}

__global__ void fold_b_kernel(const float* __restrict__ b1, const float* __restrict__ W2,
                              const float* __restrict__ bih, const float* __restrict__ bhh,
                              float* __restrict__ bf, int K, int N) {
    int n = blockIdx.x * blockDim.x + threadIdx.x;
    if (n >= N) return;
    float acc = bih[n] + bhh[n];
    for (int k = 0; k < K; ++k) acc = fmaf(b1[k], W2[k * N + n], acc);
    bf[n] = acc;
}

// ---------- rel input: first frame absolute xy, then deltas; psi,v passthrough ----------
__global__ void rel_kernel(const float* __restrict__ traj, float* __restrict__ rel) {
    int id = blockIdx.x * blockDim.x + threadIdx.x;
    if (id >= B_ * T_) return;
    int t = id % T_;
    const float* p = traj + (size_t)id * 4;
    float x = p[0], y = p[1];
    if (t > 0) { x -= p[-4]; y -= p[-3]; }
    float* o = rel + (size_t)id * 4;
    o[0] = x; o[1] = y; o[2] = p[2]; o[3] = p[3];
}

__global__ void copy4_kernel(const float4* __restrict__ src, float4* __restrict__ dst, int n4) {
    int id = blockIdx.x * blockDim.x + threadIdx.x;
    if (id < n4) dst[id] = src[id];
}

// ---------- dual GEMM: C = Xs(Mx4,ld=ldx)@Wx(4xN) + Hm(MxKH)@Wh(KHxN) + bias; act=leaky ----------
__global__ __launch_bounds__(256) void dualgemm_kernel(
    const float* __restrict__ Xs, int ldx,
    const float* __restrict__ Wx,
    const float* __restrict__ Hm,
    const float* __restrict__ Wh,
    const float* __restrict__ bias,
    float* __restrict__ C,
    int N, int KH, int act)
{
    __shared__ float sA[16][64];   // transposed H tile
    __shared__ float sB[16][64];

    const int tid = threadIdx.x;
    const int tx = tid & 15, ty = tid >> 4;
    const int rowBase = blockIdx.x * 64;
    const int colBase = blockIdx.y * 64;

    float acc[4][4] = {{0.f, 0.f, 0.f, 0.f}, {0.f, 0.f, 0.f, 0.f},
                       {0.f, 0.f, 0.f, 0.f}, {0.f, 0.f, 0.f, 0.f}};

    if (Xs) {
        __shared__ float sX[64][4];
        __shared__ float sWx[4][64];
        {
            int r = tid >> 2, k = tid & 3;
            sX[r][k] = Xs[(size_t)(rowBase + r) * ldx + k];
            int kk = tid >> 6, n = tid & 63;
            sWx[kk][n] = Wx[kk * N + colBase + n];
        }
        __syncthreads();
        #pragma unroll
        for (int k = 0; k < 4; ++k) {
            float a[4], b[4];
            #pragma unroll
            for (int i = 0; i < 4; ++i) a[i] = sX[ty * 4 + i][k];
            #pragma unroll
            for (int j = 0; j < 4; ++j) b[j] = sWx[k][tx * 4 + j];
            #pragma unroll
            for (int i = 0; i < 4; ++i)
                #pragma unroll
                for (int j = 0; j < 4; ++j)
                    acc[i][j] = fmaf(a[i], b[j], acc[i][j]);
        }
    }

    for (int k0 = 0; k0 < KH; k0 += 16) {
        const int r = tid >> 2, q = tid & 3;
        float4 hv = *reinterpret_cast<const float4*>(&Hm[(size_t)(rowBase + r) * KH + k0 + q * 4]);
        const int kk = tid >> 4, nq = tid & 15;
        float4 wv = *reinterpret_cast<const float4*>(&Wh[(size_t)(k0 + kk) * N + colBase + nq * 4]);
        __syncthreads();
        sA[q * 4 + 0][r] = hv.x;
        sA[q * 4 + 1][r] = hv.y;
        sA[q * 4 + 2][r] = hv.z;
        sA[q * 4 + 3][r] = hv.w;
        *reinterpret_cast<float4*>(&sB[kk][nq * 4]) = wv;
        __syncthreads();
        #pragma unroll
        for (int kx = 0; kx < 16; ++kx) {
            float4 av = *reinterpret_cast<const float4*>(&sA[kx][ty * 4]);
            float4 bv = *reinterpret_cast<const float4*>(&sB[kx][tx * 4]);
            float a[4] = {av.x, av.y, av.z, av.w};
            float b[4] = {bv.x, bv.y, bv.z, bv.w};
            #pragma unroll
            for (int i = 0; i < 4; ++i)
                #pragma unroll
                for (int j = 0; j < 4; ++j)
                    acc[i][j] = fmaf(a[i], b[j], acc[i][j]);
        }
    }

    #pragma unroll
    for (int i = 0; i < 4; ++i) {
        const int row = rowBase + ty * 4 + i;
        float4 outv;
        float* po = &outv.x;
        #pragma unroll
        for (int j = 0; j < 4; ++j) {
            float v = acc[i][j] + bias[colBase + tx * 4 + j];
            if (act) v = (v > 0.f) ? v : 0.01f * v;
            po[j] = v;
        }
        *reinterpret_cast<float4*>(&C[(size_t)row * N + colBase + tx * 4]) = outv;
    }
}

// ---------- LSTM pointwise update ----------
__global__ __launch_bounds__(256) void lstm_update_kernel(
    const float* __restrict__ G, float* __restrict__ h, float* __restrict__ c)
{
    int id = blockIdx.x * blockDim.x + threadIdx.x;  // over B*H
    int b = id >> 8;
    int j = id & 255;
    const float* g = G + (size_t)b * NG_;
    float gi = g[j], gf = g[H_ + j], gg = g[2 * H_ + j], go = g[3 * H_ + j];
    float iv = 1.f / (1.f + expf(-gi));
    float fv = 1.f / (1.f + expf(-gf));
    float gv = tanhf(gg);
    float ov = 1.f / (1.f + expf(-go));
    float cn = fv * c[id] + iv * gv;
    c[id] = cn;
    h[id] = ov * tanhf(cn);
}

// ---------- z = tanh(eps*exp(0.5*lv)+mu) ----------
__global__ void z_kernel(const float* __restrict__ eps, const float* __restrict__ mu,
                         const float* __restrict__ lv, float* __restrict__ z) {
    int id = blockIdx.x * blockDim.x + threadIdx.x;  // B*H
    z[id] = tanhf(eps[id] * expf(0.5f * lv[id]) + mu[id]);
}

// ---------- decoder ctrl head + bicycle dynamics: one wave per batch row ----------
__global__ __launch_bounds__(256) void dec_ctrl_dyn_kernel(
    const float* __restrict__ h, const float* __restrict__ Wc, const float* __restrict__ bc,
    float* __restrict__ s, float* __restrict__ recons, int t)
{
    int lane = threadIdx.x & 63;
    int b = blockIdx.x * 4 + (threadIdx.x >> 6);
    float4 hv = *reinterpret_cast<const float4*>(&h[(size_t)b * H_ + lane * 4]);
    float4 w0 = *reinterpret_cast<const float4*>(&Wc[lane * 8]);      // rows 4l..4l+1
    float4 w1 = *reinterpret_cast<const float4*>(&Wc[lane * 8 + 4]);  // rows 4l+2..4l+3
    float a0 = hv.x * w0.x + hv.y * w0.z + hv.z * w1.x + hv.w * w1.z;
    float a1 = hv.x * w0.y + hv.y * w0.w + hv.z * w1.y + hv.w * w1.w;
    #pragma unroll
    for (int off = 32; off > 0; off >>= 1) {
        a0 += __shfl_down(a0, off);
        a1 += __shfl_down(a1, off);
    }
    if (lane == 0) {
        float pedal = a0 + bc[0];
        float steer = fminf(fmaxf(a1 + bc[1], -0.5f), 0.5f);
        float4 sv = *reinterpret_cast<const float4*>(&s[(size_t)b * 4]);
        float v = sv.w;
        float v1 = fminf(fmaxf(v + pedal * DT_, 0.f), 10.f);
        float pd = fminf(fmaxf(v * tanf(steer) / 2.5f, -1.57f), 1.57f);
        float4 ns;
        ns.x = sv.x + v1 * cosf(sv.z) * DT_;
        ns.y = sv.y + v1 * sinf(sv.z) * DT_;
        ns.z = sv.z + pd * DT_;
        ns.w = v1;
        *reinterpret_cast<float4*>(&s[(size_t)b * 4]) = ns;
        *reinterpret_cast<float4*>(&recons[((size_t)b * T_ + t) * 4]) = ns;
    }
}

extern "C" void kernel_launch(void* const* d_in, const int* in_sizes, int n_in,
                              void* d_out, int out_size, void* d_ws, size_t ws_size,
                              hipStream_t stream) {
    (void)in_sizes; (void)n_in; (void)out_size; (void)ws_size;
    const float* traj       = (const float*)d_in[0];
    const float* init_s     = (const float*)d_in[1];
    const float* eps        = (const float*)d_in[2];
    const float* enc_emb_W  = (const float*)d_in[3];
    const float* enc_emb_b  = (const float*)d_in[4];
    const float* enc_Wih    = (const float*)d_in[5];
    const float* enc_bih    = (const float*)d_in[6];
    const float* enc_Whh    = (const float*)d_in[7];
    const float* enc_bhh    = (const float*)d_in[8];
    const float* mu_W       = (const float*)d_in[9];
    const float* mu_b       = (const float*)d_in[10];
    const float* lv_W       = (const float*)d_in[11];
    const float* lv_b       = (const float*)d_in[12];
    const float* dec_emb_W  = (const float*)d_in[13];
    const float* dec_emb_b  = (const float*)d_in[14];
    const float* dec_init_W = (const float*)d_in[15];
    const float* dec_init_b = (const float*)d_in[16];
    const float* dec_Wih    = (const float*)d_in[17];
    const float* dec_bih    = (const float*)d_in[18];
    const float* dec_Whh    = (const float*)d_in[19];
    const float* dec_bhh    = (const float*)d_in[20];
    const float* ctrl_W     = (const float*)d_in[21];
    const float* ctrl_b     = (const float*)d_in[22];

    float* out = (float*)d_out;
    float* recons = out;                              // B*T*4
    float* expert = out + (size_t)B_ * T_ * 4;        // B*T*4
    float* mu_out = expert + (size_t)B_ * T_ * 4;     // B*H
    float* lv_out = mu_out + (size_t)B_ * H_;         // B*H

    float* ws = (float*)d_ws;
    size_t o = 0;
    float* rel   = ws + o; o += (size_t)B_ * T_ * 4;
    float* h     = ws + o; o += (size_t)B_ * H_;
    float* c     = ws + o; o += (size_t)B_ * H_;
    float* gates = ws + o; o += (size_t)B_ * NG_;
    float* t0    = ws + o; o += (size_t)B_ * H_;
    float* t1    = ws + o; o += (size_t)B_ * H_;
    float* s     = ws + o; o += (size_t)B_ * 4;
    float* WfE   = ws + o; o += 4 * NG_;
    float* bfE   = ws + o; o += NG_;
    float* WfD   = ws + o; o += 4 * NG_;
    float* bfD   = ws + o; o += NG_;

    // weight folds (exact: emb is linear into the LSTM input GEMM)
    fold_w_kernel<<<16, 256, 0, stream>>>(enc_emb_W, enc_Wih, WfE, 128, NG_);
    fold_b_kernel<<<4, 256, 0, stream>>>(enc_emb_b, enc_Wih, enc_bih, enc_bhh, bfE, 128, NG_);
    fold_w_kernel<<<16, 256, 0, stream>>>(dec_emb_W, dec_Wih, WfD, 128, NG_);
    fold_b_kernel<<<4, 256, 0, stream>>>(dec_emb_b, dec_Wih, dec_bih, dec_bhh, bfD, 128, NG_);

    rel_kernel<<<(B_ * T_ + 255) / 256, 256, 0, stream>>>(traj, rel);
    copy4_kernel<<<(B_ * T_ + 255) / 256, 256, 0, stream>>>(
        (const float4*)traj, (float4*)expert, B_ * T_);

    hipMemsetAsync(h, 0, (size_t)B_ * H_ * sizeof(float), stream);
    hipMemsetAsync(c, 0, (size_t)B_ * H_ * sizeof(float), stream);

    dim3 gridG(B_ / 64, NG_ / 64);
    dim3 gridM(B_ / 64, H_ / 64);

    // encoder LSTM
    for (int t = 0; t < T_; ++t) {
        dualgemm_kernel<<<gridG, 256, 0, stream>>>(rel + t * 4, T_ * 4, WfE, h, enc_Whh,
                                                   bfE, gates, NG_, H_, 0);
        lstm_update_kernel<<<B_ * H_ / 256, 256, 0, stream>>>(gates, h, c);
    }

    // mu / lv MLPs (4 layers each, leaky_relu)
    dualgemm_kernel<<<gridM, 256, 0, stream>>>(nullptr, 0, nullptr, h,  mu_W + 0 * 65536, mu_b + 0,   t0,     H_, H_, 1);
    dualgemm_kernel<<<gridM, 256, 0, stream>>>(nullptr, 0, nullptr, t0, mu_W + 1 * 65536, mu_b + 256, t1,     H_, H_, 1);
    dualgemm_kernel<<<gridM, 256, 0, stream>>>(nullptr, 0, nullptr, t1, mu_W + 2 * 65536, mu_b + 512, t0,     H_, H_, 1);
    dualgemm_kernel<<<gridM, 256, 0, stream>>>(nullptr, 0, nullptr, t0, mu_W + 3 * 65536, mu_b + 768, mu_out, H_, H_, 1);
    dualgemm_kernel<<<gridM, 256, 0, stream>>>(nullptr, 0, nullptr, h,  lv_W + 0 * 65536, lv_b + 0,   t0,     H_, H_, 1);
    dualgemm_kernel<<<gridM, 256, 0, stream>>>(nullptr, 0, nullptr, t0, lv_W + 1 * 65536, lv_b + 256, t1,     H_, H_, 1);
    dualgemm_kernel<<<gridM, 256, 0, stream>>>(nullptr, 0, nullptr, t1, lv_W + 2 * 65536, lv_b + 512, t0,     H_, H_, 1);
    dualgemm_kernel<<<gridM, 256, 0, stream>>>(nullptr, 0, nullptr, t0, lv_W + 3 * 65536, lv_b + 768, lv_out, H_, H_, 1);

    // z, decoder init
    z_kernel<<<B_ * H_ / 256, 256, 0, stream>>>(eps, mu_out, lv_out, t0);
    dualgemm_kernel<<<gridM, 256, 0, stream>>>(nullptr, 0, nullptr, t0, dec_init_W, dec_init_b, h, H_, H_, 0);
    copy4_kernel<<<(B_ * H_ / 4 + 255) / 256, 256, 0, stream>>>((const float4*)h, (float4*)c, B_ * H_ / 4);
    copy4_kernel<<<(B_ + 255) / 256, 256, 0, stream>>>((const float4*)init_s, (float4*)s, B_);

    // decoder LSTM + dynamics
    for (int t = 0; t < T_; ++t) {
        dualgemm_kernel<<<gridG, 256, 0, stream>>>(s, 4, WfD, h, dec_Whh, bfD, gates, NG_, H_, 0);
        lstm_update_kernel<<<B_ * H_ / 256, 256, 0, stream>>>(gates, h, c);
        dec_ctrl_dyn_kernel<<<B_ / 4, 256, 0, stream>>>(h, ctrl_W, ctrl_b, s, recons, t);
    }
}

// Round 2
// 1631.031 us; speedup vs baseline: 2.8734x; 2.8734x over previous
//
#include <hip/hip_runtime.h>
#include <hip/hip_bf16.h>
#include <math.h>

#define B_ 8192
#define T_ 30
#define H_ 256
#define NG_ 1024  // 4*H
#define DT_ 0.03f

typedef __attribute__((ext_vector_type(8))) short short8;
typedef __attribute__((ext_vector_type(4))) float f32x4;

__device__ inline float bf2f(unsigned short u) {
    unsigned int x = ((unsigned int)u) << 16;
    return __builtin_bit_cast(float, x);
}
__device__ inline unsigned short f2bf(float f) {  // RNE, no NaN concerns here
    unsigned int x = __builtin_bit_cast(unsigned int, f);
    return (unsigned short)((x + 0x7FFF + ((x >> 16) & 1)) >> 16);
}
__device__ inline float fast_tanh(float x) {
    float e = __expf(2.f * x);
    return 1.f - 2.f / (e + 1.f);
}
__device__ inline float fast_sigmoid(float x) {
    return 1.f / (1.f + __expf(-x));
}

// ---------- fold: Wf = W1(4xK) @ W2(KxN); bf = b1@W2 + bih + bhh ----------
__global__ void fold_w_kernel(const float* __restrict__ W1, const float* __restrict__ W2,
                              float* __restrict__ Wf, int K, int N) {
    int id = blockIdx.x * blockDim.x + threadIdx.x;
    if (id >= 4 * N) return;
    int r = id / N, n = id % N;
    float acc = 0.f;
    for (int k = 0; k < K; ++k) acc = fmaf(W1[r * K + k], W2[k * N + n], acc);
    Wf[r * N + n] = acc;
}

__global__ void fold_b_kernel(const float* __restrict__ b1, const float* __restrict__ W2,
                              const float* __restrict__ bih, const float* __restrict__ bhh,
                              float* __restrict__ bf, int K, int N) {
    int n = blockIdx.x * blockDim.x + threadIdx.x;
    if (n >= N) return;
    float acc = bih[n] + bhh[n];
    for (int k = 0; k < K; ++k) acc = fmaf(b1[k], W2[k * N + n], acc);
    bf[n] = acc;
}

// permute fold outputs into gate-interleaved n' layout:
// n' = bN*64 + g*16 + j  <->  orig col = g*256 + bN*16 + j
__global__ void permute_fold_kernel(const float* __restrict__ Wf, const float* __restrict__ bf,
                                    float* __restrict__ WxP, float* __restrict__ bfP) {
    int np = blockIdx.x * blockDim.x + threadIdx.x;
    if (np >= NG_) return;
    int bN = np >> 6, r = np & 63, g = r >> 4, j = r & 15;
    int co = g * 256 + bN * 16 + j;
    bfP[np] = bf[co];
    #pragma unroll
    for (int k = 0; k < 4; ++k) WxP[k * NG_ + np] = Wf[k * NG_ + co];
}

// WhP[n'][k] = bf16(Whh[k][orig_col(n')])   (1024 x 256)
__global__ void prep_whp_kernel(const float* __restrict__ W, unsigned short* __restrict__ WhP) {
    int id = blockIdx.x * blockDim.x + threadIdx.x;  // 1024*256
    int np = id >> 8, k = id & 255;
    int bN = np >> 6, r = np & 63, g = r >> 4, j = r & 15;
    int co = g * 256 + bN * 16 + j;
    WhP[id] = f2bf(W[(size_t)k * NG_ + co]);
}

// WT[n][k] = bf16(W[k][n])  for 256x256 MLP weights
__global__ void prep_wt_kernel(const float* __restrict__ W, unsigned short* __restrict__ WT) {
    int id = blockIdx.x * blockDim.x + threadIdx.x;  // 65536
    int n = id >> 8, k = id & 255;
    WT[id] = f2bf(W[k * H_ + n]);
}

// ---------- rel input ----------
__global__ void rel_kernel(const float* __restrict__ traj, float* __restrict__ rel) {
    int id = blockIdx.x * blockDim.x + threadIdx.x;
    if (id >= B_ * T_) return;
    int t = id % T_;
    const float* p = traj + (size_t)id * 4;
    float x = p[0], y = p[1];
    if (t > 0) { x -= p[-4]; y -= p[-3]; }
    float* o = rel + (size_t)id * 4;
    o[0] = x; o[1] = y; o[2] = p[2]; o[3] = p[3];
}

__global__ void copy4_kernel(const float4* __restrict__ src, float4* __restrict__ dst, int n4) {
    int id = blockIdx.x * blockDim.x + threadIdx.x;
    if (id < n4) dst[id] = src[id];
}

// ---------- fused LSTM step: gates = Hin@WhP^T (MFMA) + Xs@WxP + biasP; pointwise; ----------
// gate-permuted N layout: block owns 16 units x 4 gates. h bf16 ping-pong, c fp32 in-place.
__global__ __launch_bounds__(256) void lstm_step_kernel(
    const float* __restrict__ Xs, int ldx,
    const float* __restrict__ WxP,            // [4][1024] permuted
    const unsigned short* __restrict__ Hin,   // [B][256] bf16
    const unsigned short* __restrict__ WhP,   // [1024][256] bf16, rows = n'
    const float* __restrict__ biasP,          // [1024] permuted
    float* __restrict__ Cst,                  // [B][256] fp32
    unsigned short* __restrict__ Hout)        // [B][256] bf16
{
    __shared__ __align__(16) short sA[64 * 256];
    __shared__ __align__(16) short sB[64 * 256];
    const int tid = threadIdx.x;
    const int lane = tid & 63;
    const int wr = (tid >> 7) & 1;
    const int wc = (tid >> 6) & 1;
    const int rowBase = blockIdx.x * 64;
    const int nBase = blockIdx.y * 64;

    // stage A,B tiles (64x256 bf16 each) with XOR-swizzle on 16B slots
    {
        const unsigned short* gA = Hin + (size_t)rowBase * 256;
        const unsigned short* gB = WhP + (size_t)nBase * 256;
        #pragma unroll
        for (int i = 0; i < 8; ++i) {
            int ch = tid + i * 256;           // 2048 chunks of 16B
            int row = ch >> 5, slot = ch & 31;
            float4 va = *(const float4*)(gA + row * 256 + slot * 8);
            float4 vb = *(const float4*)(gB + row * 256 + slot * 8);
            int sl = slot ^ (row & 7);
            *(float4*)(sA + row * 256 + sl * 8) = va;
            *(float4*)(sB + row * 256 + sl * 8) = vb;
        }
    }
    __syncthreads();

    const int fr = lane & 15;   // frag row (A) / col (B,D)
    const int kg = lane >> 4;   // k-group
    f32x4 acc[2][2] = {};
    #pragma unroll
    for (int k0 = 0; k0 < 8; ++k0) {
        int kch = k0 * 4 + kg;
        short8 a[2], b[2];
        #pragma unroll
        for (int m = 0; m < 2; ++m) {
            int r = wr * 32 + m * 16 + fr;
            a[m] = *(const short8*)(sA + r * 256 + (kch ^ (r & 7)) * 8);
        }
        #pragma unroll
        for (int n = 0; n < 2; ++n) {
            int r = wc * 32 + n * 16 + fr;
            b[n] = *(const short8*)(sB + r * 256 + (kch ^ (r & 7)) * 8);
        }
        #pragma unroll
        for (int m = 0; m < 2; ++m)
            #pragma unroll
            for (int n = 0; n < 2; ++n)
                acc[m][n] = __builtin_amdgcn_mfma_f32_16x16x32_bf16(a[m], b[n], acc[m][n], 0, 0, 0);
    }

    // accumulator -> LDS (reuse sA), natural [64][65] layout
    __syncthreads();
    float* sC = (float*)sA;
    #pragma unroll
    for (int m = 0; m < 2; ++m)
        #pragma unroll
        for (int n = 0; n < 2; ++n)
            #pragma unroll
            for (int r = 0; r < 4; ++r)
                sC[(wr * 32 + m * 16 + kg * 4 + r) * 65 + wc * 32 + n * 16 + fr] = acc[m][n][r];
    __syncthreads();

    // pointwise LSTM update: thread -> (row, 4 consecutive units)
    {
        const int row = tid & 63;
        const int jg = tid >> 6;   // 0..3
        float4 xv = *(const float4*)(Xs + (size_t)(rowBase + row) * ldx);
        float gv4[4][4];
        #pragma unroll
        for (int q = 0; q < 4; ++q) {
            int j = jg * 4 + q;
            #pragma unroll
            for (int g = 0; g < 4; ++g) {
                int npg = nBase + g * 16 + j;
                gv4[q][g] = sC[row * 65 + g * 16 + j] + biasP[npg]
                          + xv.x * WxP[npg] + xv.y * WxP[NG_ + npg]
                          + xv.z * WxP[2 * NG_ + npg] + xv.w * WxP[3 * NG_ + npg];
            }
        }
        size_t base = (size_t)(rowBase + row) * H_ + (nBase >> 2) + jg * 4;
        float4 cv = *(float4*)(Cst + base);
        float cc[4] = {cv.x, cv.y, cv.z, cv.w};
        ushort4 ho;
        unsigned short* hop = (unsigned short*)&ho;
        #pragma unroll
        for (int q = 0; q < 4; ++q) {
            float iv = fast_sigmoid(gv4[q][0]);
            float fv = fast_sigmoid(gv4[q][1]);
            float gg = fast_tanh(gv4[q][2]);
            float ov = fast_sigmoid(gv4[q][3]);
            float cn = fv * cc[q] + iv * gg;
            cc[q] = cn;
            hop[q] = f2bf(ov * fast_tanh(cn));
        }
        cv.x = cc[0]; cv.y = cc[1]; cv.z = cc[2]; cv.w = cc[3];
        *(float4*)(Cst + base) = cv;
        *(ushort4*)(Hout + base) = ho;
    }
}

// ---------- MFMA GEMM for MLP layers: C = A(Bx256)@WT^T + bias [; leaky] ----------
__global__ __launch_bounds__(256) void mlp_gemm_kernel(
    const unsigned short* __restrict__ Ain,  // [B][256] bf16
    const unsigned short* __restrict__ WT,   // [256][256] bf16, rows = n
    const float* __restrict__ bias,
    float* __restrict__ outF,                // optional
    unsigned short* __restrict__ outB,       // optional
    int act)
{
    __shared__ __align__(16) short sA[64 * 256];
    __shared__ __align__(16) short sB[64 * 256];
    const int tid = threadIdx.x;
    const int lane = tid & 63;
    const int wr = (tid >> 7) & 1;
    const int wc = (tid >> 6) & 1;
    const int rowBase = blockIdx.x * 64;
    const int nBase = blockIdx.y * 64;

    {
        const unsigned short* gA = Ain + (size_t)rowBase * 256;
        const unsigned short* gB = WT + (size_t)nBase * 256;
        #pragma unroll
        for (int i = 0; i < 8; ++i) {
            int ch = tid + i * 256;
            int row = ch >> 5, slot = ch & 31;
            float4 va = *(const float4*)(gA + row * 256 + slot * 8);
            float4 vb = *(const float4*)(gB + row * 256 + slot * 8);
            int sl = slot ^ (row & 7);
            *(float4*)(sA + row * 256 + sl * 8) = va;
            *(float4*)(sB + row * 256 + sl * 8) = vb;
        }
    }
    __syncthreads();

    const int fr = lane & 15;
    const int kg = lane >> 4;
    f32x4 acc[2][2] = {};
    #pragma unroll
    for (int k0 = 0; k0 < 8; ++k0) {
        int kch = k0 * 4 + kg;
        short8 a[2], b[2];
        #pragma unroll
        for (int m = 0; m < 2; ++m) {
            int r = wr * 32 + m * 16 + fr;
            a[m] = *(const short8*)(sA + r * 256 + (kch ^ (r & 7)) * 8);
        }
        #pragma unroll
        for (int n = 0; n < 2; ++n) {
            int r = wc * 32 + n * 16 + fr;
            b[n] = *(const short8*)(sB + r * 256 + (kch ^ (r & 7)) * 8);
        }
        #pragma unroll
        for (int m = 0; m < 2; ++m)
            #pragma unroll
            for (int n = 0; n < 2; ++n)
                acc[m][n] = __builtin_amdgcn_mfma_f32_16x16x32_bf16(a[m], b[n], acc[m][n], 0, 0, 0);
    }

    #pragma unroll
    for (int m = 0; m < 2; ++m) {
        #pragma unroll
        for (int n = 0; n < 2; ++n) {
            int col = nBase + wc * 32 + n * 16 + fr;
            float bv = bias[col];
            #pragma unroll
            for (int r = 0; r < 4; ++r) {
                int row = rowBase + wr * 32 + m * 16 + kg * 4 + r;
                float v = acc[m][n][r] + bv;
                if (act) v = v > 0.f ? v : 0.01f * v;
                if (outF) outF[(size_t)row * H_ + col] = v;
                if (outB) outB[(size_t)row * H_ + col] = f2bf(v);
            }
        }
    }
}

// ---------- z = tanh(eps*exp(0.5*lv)+mu) -> bf16 ----------
__global__ void z_kernel(const float* __restrict__ eps, const float* __restrict__ mu,
                         const float* __restrict__ lv, unsigned short* __restrict__ z) {
    int id = blockIdx.x * blockDim.x + threadIdx.x;
    z[id] = f2bf(tanhf(eps[id] * expf(0.5f * lv[id]) + mu[id]));
}

// ---------- decoder ctrl head + bicycle dynamics (h in bf16) ----------
__global__ __launch_bounds__(256) void dec_ctrl_dyn_kernel(
    const unsigned short* __restrict__ h, const float* __restrict__ Wc, const float* __restrict__ bc,
    float* __restrict__ s, float* __restrict__ recons, int t)
{
    int lane = threadIdx.x & 63;
    int b = blockIdx.x * 4 + (threadIdx.x >> 6);
    const unsigned short* hp = h + (size_t)b * H_ + lane * 4;
    float h0 = bf2f(hp[0]), h1 = bf2f(hp[1]), h2 = bf2f(hp[2]), h3 = bf2f(hp[3]);
    float4 w0 = *reinterpret_cast<const float4*>(&Wc[lane * 8]);
    float4 w1 = *reinterpret_cast<const float4*>(&Wc[lane * 8 + 4]);
    float a0 = h0 * w0.x + h1 * w0.z + h2 * w1.x + h3 * w1.z;
    float a1 = h0 * w0.y + h1 * w0.w + h2 * w1.y + h3 * w1.w;
    #pragma unroll
    for (int off = 32; off > 0; off >>= 1) {
        a0 += __shfl_down(a0, off);
        a1 += __shfl_down(a1, off);
    }
    if (lane == 0) {
        float pedal = a0 + bc[0];
        float steer = fminf(fmaxf(a1 + bc[1], -0.5f), 0.5f);
        float4 sv = *reinterpret_cast<const float4*>(&s[(size_t)b * 4]);
        float v = sv.w;
        float v1 = fminf(fmaxf(v + pedal * DT_, 0.f), 10.f);
        float pd = fminf(fmaxf(v * tanf(steer) / 2.5f, -1.57f), 1.57f);
        float4 ns;
        ns.x = sv.x + v1 * cosf(sv.z) * DT_;
        ns.y = sv.y + v1 * sinf(sv.z) * DT_;
        ns.z = sv.z + pd * DT_;
        ns.w = v1;
        *reinterpret_cast<float4*>(&s[(size_t)b * 4]) = ns;
        *reinterpret_cast<float4*>(&recons[((size_t)b * T_ + t) * 4]) = ns;
    }
}

extern "C" void kernel_launch(void* const* d_in, const int* in_sizes, int n_in,
                              void* d_out, int out_size, void* d_ws, size_t ws_size,
                              hipStream_t stream) {
    (void)in_sizes; (void)n_in; (void)out_size; (void)ws_size;
    const float* traj       = (const float*)d_in[0];
    const float* init_s     = (const float*)d_in[1];
    const float* eps        = (const float*)d_in[2];
    const float* enc_emb_W  = (const float*)d_in[3];
    const float* enc_emb_b  = (const float*)d_in[4];
    const float* enc_Wih    = (const float*)d_in[5];
    const float* enc_bih    = (const float*)d_in[6];
    const float* enc_Whh    = (const float*)d_in[7];
    const float* enc_bhh    = (const float*)d_in[8];
    const float* mu_W       = (const float*)d_in[9];
    const float* mu_b       = (const float*)d_in[10];
    const float* lv_W       = (const float*)d_in[11];
    const float* lv_b       = (const float*)d_in[12];
    const float* dec_emb_W  = (const float*)d_in[13];
    const float* dec_emb_b  = (const float*)d_in[14];
    const float* dec_Wih    = (const float*)d_in[15];
    const float* dec_bih    = (const float*)d_in[16];
    const float* dec_init_W = (const float*)d_in[17];
    const float* dec_init_b = (const float*)d_in[18];
    // NOTE: order per setup_inputs: dec_emb(13,14), dec_init(15,16), dec_Wih(17,18)? No:
    // dict order: dec_emb_W, dec_emb_b, dec_init_W, dec_init_b, dec_Wih, dec_bih, dec_Whh, dec_bhh, ctrl_W, ctrl_b
    const float* dec_init_W_ = (const float*)d_in[15];
    const float* dec_init_b_ = (const float*)d_in[16];
    const float* dec_Wih_    = (const float*)d_in[17];
    const float* dec_bih_    = (const float*)d_in[18];
    const float* dec_Whh    = (const float*)d_in[19];
    const float* dec_bhh    = (const float*)d_in[20];
    const float* ctrl_W     = (const float*)d_in[21];
    const float* ctrl_b     = (const float*)d_in[22];
    (void)dec_init_W; (void)dec_init_b;

    float* out = (float*)d_out;
    float* recons = out;                              // B*T*4
    float* expert = out + (size_t)B_ * T_ * 4;        // B*T*4
    float* mu_out = expert + (size_t)B_ * T_ * 4;     // B*H
    float* lv_out = mu_out + (size_t)B_ * H_;         // B*H

    float* ws = (float*)d_ws;
    size_t o = 0;
    float* rel   = ws + o; o += (size_t)B_ * T_ * 4;
    float* c     = ws + o; o += (size_t)B_ * H_;
    unsigned short* hA = (unsigned short*)(ws + o); o += (size_t)B_ * H_ / 2;
    unsigned short* hB = (unsigned short*)(ws + o); o += (size_t)B_ * H_ / 2;
    unsigned short* tb0 = (unsigned short*)(ws + o); o += (size_t)B_ * H_ / 2;
    unsigned short* tb1 = (unsigned short*)(ws + o); o += (size_t)B_ * H_ / 2;
    float* s     = ws + o; o += (size_t)B_ * 4;
    unsigned short* WhPE = (unsigned short*)(ws + o); o += NG_ * H_ / 2;
    unsigned short* WhPD = (unsigned short*)(ws + o); o += NG_ * H_ / 2;
    unsigned short* WT9  = (unsigned short*)(ws + o); o += 9 * H_ * H_ / 2;
    float* WxPE  = ws + o; o += 4 * NG_;
    float* WxPD  = ws + o; o += 4 * NG_;
    float* bfPE  = ws + o; o += NG_;
    float* bfPD  = ws + o; o += NG_;
    float* Wft   = ws + o; o += 4 * NG_;
    float* bft   = ws + o; o += NG_;

    // ---- one-time prep ----
    fold_w_kernel<<<16, 256, 0, stream>>>(enc_emb_W, enc_Wih, Wft, 128, NG_);
    fold_b_kernel<<<4, 256, 0, stream>>>(enc_emb_b, enc_Wih, enc_bih, enc_bhh, bft, 128, NG_);
    permute_fold_kernel<<<4, 256, 0, stream>>>(Wft, bft, WxPE, bfPE);
    fold_w_kernel<<<16, 256, 0, stream>>>(dec_emb_W, dec_Wih_, Wft, 128, NG_);
    fold_b_kernel<<<4, 256, 0, stream>>>(dec_emb_b, dec_Wih_, dec_bih_, dec_bhh, bft, 128, NG_);
    permute_fold_kernel<<<4, 256, 0, stream>>>(Wft, bft, WxPD, bfPD);
    prep_whp_kernel<<<1024, 256, 0, stream>>>(enc_Whh, WhPE);
    prep_whp_kernel<<<1024, 256, 0, stream>>>(dec_Whh, WhPD);
    for (int i = 0; i < 4; ++i) {
        prep_wt_kernel<<<256, 256, 0, stream>>>(mu_W + (size_t)i * H_ * H_, WT9 + (size_t)i * H_ * H_);
        prep_wt_kernel<<<256, 256, 0, stream>>>(lv_W + (size_t)i * H_ * H_, WT9 + (size_t)(4 + i) * H_ * H_);
    }
    prep_wt_kernel<<<256, 256, 0, stream>>>(dec_init_W_, WT9 + (size_t)8 * H_ * H_);

    rel_kernel<<<(B_ * T_ + 255) / 256, 256, 0, stream>>>(traj, rel);
    copy4_kernel<<<(B_ * T_ + 255) / 256, 256, 0, stream>>>(
        (const float4*)traj, (float4*)expert, B_ * T_);

    hipMemsetAsync(hA, 0, (size_t)B_ * H_ * sizeof(unsigned short), stream);
    hipMemsetAsync(c, 0, (size_t)B_ * H_ * sizeof(float), stream);

    dim3 gridL(B_ / 64, NG_ / 64);   // 128 x 16
    dim3 gridM(B_ / 64, H_ / 64);    // 128 x 4

    // ---- encoder LSTM ----
    unsigned short* hin = hA;
    unsigned short* hout = hB;
    for (int t = 0; t < T_; ++t) {
        lstm_step_kernel<<<gridL, 256, 0, stream>>>(rel + t * 4, T_ * 4, WxPE, hin, WhPE, bfPE, c, hout);
        unsigned short* tmp = hin; hin = hout; hout = tmp;
    }
    // final encoder h is in `hin`

    // ---- mu / lv MLPs ----
    mlp_gemm_kernel<<<gridM, 256, 0, stream>>>(hin, WT9 + 0 * 65536, mu_b + 0,   nullptr, tb0, 1);
    mlp_gemm_kernel<<<gridM, 256, 0, stream>>>(tb0, WT9 + 1 * 65536, mu_b + 256, nullptr, tb1, 1);
    mlp_gemm_kernel<<<gridM, 256, 0, stream>>>(tb1, WT9 + 2 * 65536, mu_b + 512, nullptr, tb0, 1);
    mlp_gemm_kernel<<<gridM, 256, 0, stream>>>(tb0, WT9 + 3 * 65536, mu_b + 768, mu_out, nullptr, 1);
    mlp_gemm_kernel<<<gridM, 256, 0, stream>>>(hin, WT9 + 4 * 65536, lv_b + 0,   nullptr, tb0, 1);
    mlp_gemm_kernel<<<gridM, 256, 0, stream>>>(tb0, WT9 + 5 * 65536, lv_b + 256, nullptr, tb1, 1);
    mlp_gemm_kernel<<<gridM, 256, 0, stream>>>(tb1, WT9 + 6 * 65536, lv_b + 512, nullptr, tb0, 1);
    mlp_gemm_kernel<<<gridM, 256, 0, stream>>>(tb0, WT9 + 7 * 65536, lv_b + 768, lv_out, nullptr, 1);

    // ---- z, decoder init ----
    z_kernel<<<B_ * H_ / 256, 256, 0, stream>>>(eps, mu_out, lv_out, tb0);
    mlp_gemm_kernel<<<gridM, 256, 0, stream>>>(tb0, WT9 + 8 * 65536, dec_init_b_, c, hA, 0);
    copy4_kernel<<<(B_ + 255) / 256, 256, 0, stream>>>((const float4*)init_s, (float4*)s, B_);

    // ---- decoder LSTM + dynamics ----
    hin = hA; hout = hB;
    for (int t = 0; t < T_; ++t) {
        lstm_step_kernel<<<gridL, 256, 0, stream>>>(s, 4, WxPD, hin, WhPD, bfPD, c, hout);
        dec_ctrl_dyn_kernel<<<B_ / 4, 256, 0, stream>>>(hout, ctrl_W, ctrl_b, s, recons, t);
        unsigned short* tmp = hin; hin = hout; hout = tmp;
    }
}